// Round 16
// baseline (25.168 us; speedup 1.0000x reference)
//
#include <hip/hip_runtime.h>

// CrossConvV2 — R15: load-sharing across 2 centers. R13/R14 showed per-wave
// duty ~25%: each iter's ~300cyc VALU hangs off 6 fresh loads (~150cyc lat),
// ~2.4 resident waves can't cover. Share each loaded neighbor-pair across
// TWO centers: same loads feed 2x dependent VALU. All R14 numerics kept
// (pk_f32 asm, rcp8 batch, fdot2 f16 acc, f16x2 DPP reduce).
// Wave = (2 centers, probe-half, nn-half); 4 iters; 4096 waves.

#define NPTS   1024
#define COEFF  10.0f
#define NEG    0.3f

typedef float  v2f __attribute__((ext_vector_type(2)));
typedef __fp16 h2  __attribute__((ext_vector_type(2)));

#define CA 4.24264068f   // 2*2.12132034
#define CY 3.91968890f   // 2*1.95984445
#define CZ 1.62358830f   // 2*0.81179415

// slot -> probe index (R9/R12-validated mapping)
constexpr int M0[14] = {0,5, 1,4, 2,3, 7,6, 8,12, 10,14, 24,25};
constexpr int M1[12] = {16,19, 17,18, 20,23, 21,22, 9,13, 11,15};

// ---- VOP3P packed f32 (all operands VGPR pairs; validated R14) ----
__device__ __forceinline__ v2f pk_fma(v2f a, v2f b, v2f c) {   // a*b+c
  v2f d;
  asm("v_pk_fma_f32 %0, %1, %2, %3" : "=v"(d) : "v"(a), "v"(b), "v"(c));
  return d;
}
__device__ __forceinline__ v2f pk_fma_n(v2f a, v2f b, v2f c) { // -a*b+c
  v2f d;
  asm("v_pk_fma_f32 %0, %1, %2, %3 neg_lo:[1,0,0] neg_hi:[1,0,0]"
      : "=v"(d) : "v"(a), "v"(b), "v"(c));
  return d;
}
__device__ __forceinline__ v2f pk_add(v2f a, v2f b) {          // a+b
  v2f d;
  asm("v_pk_add_f32 %0, %1, %2" : "=v"(d) : "v"(a), "v"(b));
  return d;
}
__device__ __forceinline__ v2f pk_sub(v2f a, v2f b) {          // a-b
  v2f d;
  asm("v_pk_add_f32 %0, %1, %2 neg_lo:[0,1] neg_hi:[0,1]"
      : "=v"(d) : "v"(a), "v"(b));
  return d;
}

// ---- wave64 f16x2 DPP reduce: 2 values per op chain ----
#define DPP_H2(x, ctrl, rm, bm, bc)                                          \
  x = x + __builtin_bit_cast(h2, __builtin_amdgcn_update_dpp(                \
      0, __builtin_bit_cast(int, x), ctrl, rm, bm, bc))

__device__ __forceinline__ h2 h2_wave_sum_to_lane63(h2 x) {
  DPP_H2(x, 0x111, 0xf, 0xf, true);   // row_shr:1
  DPP_H2(x, 0x112, 0xf, 0xf, true);   // row_shr:2
  DPP_H2(x, 0x114, 0xf, 0xe, false);  // row_shr:4
  DPP_H2(x, 0x118, 0xf, 0xc, false);  // row_shr:8
  DPP_H2(x, 0x142, 0xa, 0xf, false);  // row_bcast:15
  DPP_H2(x, 0x143, 0xc, 0xf, false);  // row_bcast:31
  return x;                            // lane 63 = full sum (x2)
}

// ---- rcp8: one v_rcp for 4 t-pairs (8 values); emits packed-f16 w ----
__device__ __forceinline__ void rcp8_cvt(const v2f* t, h2* wp) {
  const float p0 = t[0].x * t[0].y, p1 = t[1].x * t[1].y;
  const float p2 = t[2].x * t[2].y, p3 = t[3].x * t[3].y;
  const float q01 = p0 * p1, q23 = p2 * p3;
  const float r   = __builtin_amdgcn_rcpf(q01 * q23);
  const float r01 = q23 * r, r23 = q01 * r;
  const float i0 = p1 * r01, i1 = p0 * r01;
  const float i2 = p3 * r23, i3 = p2 * r23;
  wp[0] = __builtin_amdgcn_cvt_pkrtz(t[0].y * i0, t[0].x * i0);
  wp[1] = __builtin_amdgcn_cvt_pkrtz(t[1].y * i1, t[1].x * i1);
  wp[2] = __builtin_amdgcn_cvt_pkrtz(t[2].y * i2, t[2].x * i2);
  wp[3] = __builtin_amdgcn_cvt_pkrtz(t[3].y * i3, t[3].x * i3);
}
__device__ __forceinline__ void rcp4_cvt(const v2f* t, h2* wp) {
  const float p0 = t[0].x * t[0].y, p1 = t[1].x * t[1].y;
  const float r  = __builtin_amdgcn_rcpf(p0 * p1);
  const float i0 = p1 * r, i1 = p0 * r;
  wp[0] = __builtin_amdgcn_cvt_pkrtz(t[0].y * i0, t[0].x * i0);
  wp[1] = __builtin_amdgcn_cvt_pkrtz(t[1].y * i1, t[1].x * i1);
}

// process one center for a loaded neighbor pair
template <int HALF>
__device__ __forceinline__ void proc_center(
    v2f pxp, v2f pyp, v2f pzp, h2 f0p, h2 f1p, h2 f2p,
    v2f cxp, v2f cyp, v2f czp, float* acc) {
  constexpr int NP = HALF ? 12 : 14;
  const v2f kCA = {CA, CA}, kCY = {CY, CY}, kCZ = {CZ, CZ};
  const v2f k6 = {6.f, 6.f}, k19 = {19.f, 19.f};

  const v2f dx = pk_sub(pxp, cxp);
  const v2f dy = pk_sub(pyp, cyp);
  const v2f dz = pk_sub(pzp, czp);
  v2f base = pk_fma(dz, dz, k19);
  base = pk_fma(dy, dy, base);
  base = pk_fma(dx, dx, base);

  v2f t[NP];
  if constexpr (HALF == 0) {
    const v2f rx = pk_fma(kCA, dx, base);     // ring x=-2.1213
    const v2f sA = pk_fma  (kCZ, dz, rx);
    const v2f sB = pk_fma_n(kCZ, dz, rx);
    const v2f sC = pk_fma_n(kCY, dz, rx);
    const v2f sD = pk_fma  (kCY, dz, rx);
    t[0]  = pk_fma_n(kCY, dy, sA);  t[1]  = pk_fma(kCY, dy, sA);  // p0,p5
    t[2]  = pk_fma_n(kCY, dy, sB);  t[3]  = pk_fma(kCY, dy, sB);  // p1,p4
    t[4]  = pk_fma_n(kCZ, dy, sC);  t[5]  = pk_fma(kCZ, dy, sC);  // p2,p3
    t[6]  = pk_fma_n(kCZ, dy, sD);  t[7]  = pk_fma(kCZ, dy, sD);  // p7,p6
    t[8]  = pk_fma_n(k6, dy, base); t[9]  = pk_fma(k6, dy, base); // p8,p12
    t[10] = pk_fma_n(k6, dz, base); t[11] = pk_fma(k6, dz, base); // p10,p14
    t[12] = pk_fma  (k6, dx, base); t[13] = pk_fma_n(k6, dx, base);// p24,p25
  } else {
    const v2f rx = pk_fma_n(kCA, dx, base);   // ring x=+2.1213
    const v2f sA = pk_fma_n(kCZ, dz, rx);
    const v2f sB = pk_fma_n(kCY, dz, rx);
    const v2f sC = pk_fma  (kCZ, dz, rx);
    const v2f sD = pk_fma  (kCY, dz, rx);
    const v2f u = pk_add(dy, dz), v = pk_sub(dy, dz);
    t[0]  = pk_fma_n(kCY, dy, sA);  t[1]  = pk_fma(kCY, dy, sA);  // p16,p19
    t[2]  = pk_fma_n(kCZ, dy, sB);  t[3]  = pk_fma(kCZ, dy, sB);  // p17,p18
    t[4]  = pk_fma  (kCY, dy, sC);  t[5]  = pk_fma_n(kCY, dy, sC);// p20,p23
    t[6]  = pk_fma  (kCZ, dy, sD);  t[7]  = pk_fma_n(kCZ, dy, sD);// p21,p22
    t[8]  = pk_fma_n(kCA, u, base); t[9]  = pk_fma(kCA, u, base); // p9,p13
    t[10] = pk_fma  (kCA, v, base); t[11] = pk_fma_n(kCA, v, base);// p11,p15
  }

  h2 wp[NP];
  rcp8_cvt(t + 0, wp + 0);
  rcp8_cvt(t + 4, wp + 4);
  rcp8_cvt(t + 8, wp + 8);
  if constexpr (NP == 14) rcp4_cvt(t + 12, wp + 12);

  #pragma unroll
  for (int j = 0; j < NP; ++j) {
    acc[j * 3 + 0] = __builtin_amdgcn_fdot2(wp[j], f0p, acc[j * 3 + 0], false);
    acc[j * 3 + 1] = __builtin_amdgcn_fdot2(wp[j], f1p, acc[j * 3 + 1], false);
    acc[j * 3 + 2] = __builtin_amdgcn_fdot2(wp[j], f2p, acc[j * 3 + 2], false);
  }
}

template <int HALF>
__device__ void run_main(const float* __restrict__ batch, int row0, int lane,
                         v2f cx0, v2f cy0, v2f cz0,
                         v2f cx1, v2f cy1, v2f cz1,
                         float* acc0, float* acc1) {
  for (int it = 0; it < 4; ++it) {   // nn-half: 4 x 128 neighbors
    const float* prowA = batch + (row0 + it * 128 + lane) * 6;
    const float* prowB = prowA + 64 * 6;
    const float2 a0 = *reinterpret_cast<const float2*>(prowA);
    const float2 a1 = *reinterpret_cast<const float2*>(prowA + 2);
    const float2 a2 = *reinterpret_cast<const float2*>(prowA + 4);
    const float2 b0 = *reinterpret_cast<const float2*>(prowB);
    const float2 b1 = *reinterpret_cast<const float2*>(prowB + 2);
    const float2 b2 = *reinterpret_cast<const float2*>(prowB + 4);

    const v2f pxp = {a0.x, b0.x};
    const v2f pyp = {a0.y, b0.y};
    const v2f pzp = {a1.x, b1.x};
    const h2 f0p = __builtin_amdgcn_cvt_pkrtz(a1.y, b1.y);
    const h2 f1p = __builtin_amdgcn_cvt_pkrtz(a2.x, b2.x);
    const h2 f2p = __builtin_amdgcn_cvt_pkrtz(a2.y, b2.y);

    // the SAME loaded pair feeds both centers (2x VALU per load stall)
    proc_center<HALF>(pxp, pyp, pzp, f0p, f1p, f2p, cx0, cy0, cz0, acc0);
    proc_center<HALF>(pxp, pyp, pzp, f0p, f1p, f2p, cx1, cy1, cz1, acc1);
  }
}

// packed f16x2 reduce of NP*3 accs; lane 63 unpacks into f32 sx slot
template <int HALF>
__device__ __forceinline__ void reduce_store(float* acc, int lane, float* sx) {
  constexpr int NP = HALF ? 12 : 14;
  constexpr int NH = NP * 3 / 2;            // 21 or 18 h2 regs
  h2 red[NH];
  #pragma unroll
  for (int p = 0; p < NH; ++p)
    red[p] = __builtin_amdgcn_cvt_pkrtz(acc[2 * p], acc[2 * p + 1]);
  #pragma unroll
  for (int p = 0; p < NH; ++p)
    red[p] = h2_wave_sum_to_lane63(red[p]);
  if (lane == 63) {
    #pragma unroll
    for (int p = 0; p < NH; ++p) {
      const int a0 = 2 * p, a1 = 2 * p + 1;
      const int m0 = (HALF ? M1[a0 / 3] : M0[a0 / 3]);
      const int m1 = (HALF ? M1[a1 / 3] : M0[a1 / 3]);
      sx[m0 * 3 + a0 % 3] = (float)red[p].x;
      sx[m1 * 3 + a1 % 3] = (float)red[p].y;
    }
  }
}

__global__ __launch_bounds__(256) void crossconv_kernel(
    const float* __restrict__ points,  // (2,1024,6)
    const float* __restrict__ W,       // (5,78,6)
    const float* __restrict__ bias,    // (5,6) flat 30
    float* __restrict__ out)           // (2,1024,33)
{
    // sx[center][nnHalf][value]
    __shared__ __align__(16) float sx[2][2][80];

    const int tid  = threadIdx.x;
    const int lane = tid & 63;
    const int w    = tid >> 6;            // wave in block: 0..3
    const int half = w & 1;               // probe half
    const int nnH  = w >> 1;              // neighbor half
    const int G0   = blockIdx.x * 2;      // centers G0, G0+1

    const float* batch = points + (G0 >> 10) * (NPTS * 6);
    const float* cr0   = points + G0 * 6;
    const float* cr1   = cr0 + 6;
    const float cx0 = cr0[0], cy0 = cr0[1], cz0 = cr0[2];
    const float cx1 = cr1[0], cy1 = cr1[1], cz1 = cr1[2];
    const v2f cx0p = {cx0, cx0}, cy0p = {cy0, cy0}, cz0p = {cz0, cz0};
    const v2f cx1p = {cx1, cx1}, cy1p = {cy1, cy1}, cz1p = {cz1, cz1};
    const int row0 = nnH * (NPTS / 2);

    float acc0[42], acc1[42];
    #pragma unroll
    for (int j = 0; j < 42; ++j) { acc0[j] = 0.f; acc1[j] = 0.f; }

    if (half == 0)
      run_main<0>(batch, row0, lane, cx0p, cy0p, cz0p, cx1p, cy1p, cz1p, acc0, acc1);
    else
      run_main<1>(batch, row0, lane, cx0p, cy0p, cz0p, cx1p, cy1p, cz1p, acc0, acc1);

    if (half == 0) {
      reduce_store<0>(acc0, lane, sx[0][nnH]);
      reduce_store<0>(acc1, lane, sx[1][nnH]);
    } else {
      reduce_store<1>(acc0, lane, sx[0][nnH]);
      reduce_store<1>(acc1, lane, sx[1][nnH]);
    }
    __syncthreads();

    // tail: wave 0 -> center 0, wave 1 -> center 1
    if (w < 2) {
      const int   c  = w;
      const int   G  = G0 + c;
      const float cx = c ? cx1 : cx0, cy = c ? cy1 : cy0, cz = c ? cz1 : cz0;
      const float scale = COEFF / (float)NPTS;
      float* orow = out + G * 33;
      if (lane < 30) {
        const int k = lane / 6, o = lane % 6;
        const float* Wk = W + k * (78 * 6) + o;  // W[k, t, o], stride 6 over t
        float h0 = 0.f, h1 = 0.f, h2_ = 0.f, h3 = 0.f;
        const float4* s0 = reinterpret_cast<const float4*>(sx[c][0]);
        const float4* s1 = reinterpret_cast<const float4*>(sx[c][1]);
        #pragma unroll
        for (int t4 = 0; t4 < 19; ++t4) {
          const float4 va = s0[t4], vb = s1[t4];
          h0  = fmaf(va.x + vb.x, Wk[(t4 * 4 + 0) * 6], h0);
          h1  = fmaf(va.y + vb.y, Wk[(t4 * 4 + 1) * 6], h1);
          h2_ = fmaf(va.z + vb.z, Wk[(t4 * 4 + 2) * 6], h2_);
          h3  = fmaf(va.w + vb.w, Wk[(t4 * 4 + 3) * 6], h3);
        }
        h0 = fmaf(sx[c][0][76] + sx[c][1][76], Wk[76 * 6], h0);
        h1 = fmaf(sx[c][0][77] + sx[c][1][77], Wk[77 * 6], h1);
        const float dot = (h0 + h2_) + (h1 + h3);
        float h = fmaf(dot, scale, bias[lane]);
        h = (h > 0.f) ? h : NEG * h;
        orow[3 + lane] = h;
      } else if (lane < 33) {
        orow[lane - 30] = (lane == 30) ? cx : ((lane == 31) ? cy : cz);
      }
    }
}

extern "C" void kernel_launch(void* const* d_in, const int* in_sizes, int n_in,
                              void* d_out, int out_size, void* d_ws, size_t ws_size,
                              hipStream_t stream) {
    const float* points = (const float*)d_in[0];  // 2*1024*6
    const float* W      = (const float*)d_in[1];  // 5*78*6
    const float* bias   = (const float*)d_in[2];  // 30
    float* out          = (float*)d_out;          // 2*1024*33
    // 1024 blocks x 4 waves; block = 2 centers x (probe-half x nn-half)
    crossconv_kernel<<<1024, 256, 0, stream>>>(points, W, bias, out);
}

// Round 17
// 21.440 us; speedup vs baseline: 1.1739x; 1.1739x over previous
//
#include <hip/hip_runtime.h>

// CrossConvV2 — R16: SoA transpose in LDS. Every prior variant (global AND
// R6's LDS stage) kept the 24B row stride -> each wave-load touches ~24
// cache lines / multi-way LDS bank groups on the per-CU shared memory pipe.
// That pipe saturates at ~60% VALU duty regardless of occupancy (R13), which
// explains 8 flat rounds. Fix: one-time per-block transpose into 6 LDS
// component arrays; inner loop = 6 conflict-free stride-8B ds_read_b64 per
// 2-neighbor iter (pairs (2i,2i+1)). R14 numerics kept verbatim.

#define NPTS   1024
#define COEFF  10.0f
#define NEG    0.3f

typedef float  v2f __attribute__((ext_vector_type(2)));
typedef __fp16 h2  __attribute__((ext_vector_type(2)));

#define CA 4.24264068f   // 2*2.12132034
#define CY 3.91968890f   // 2*1.95984445
#define CZ 1.62358830f   // 2*0.81179415

// slot -> probe index (R9/R12-validated mapping)
constexpr int M0[14] = {0,5, 1,4, 2,3, 7,6, 8,12, 10,14, 24,25};
constexpr int M1[12] = {16,19, 17,18, 20,23, 21,22, 9,13, 11,15};

// ---- VOP3P packed f32 (all operands VGPR pairs; validated R14) ----
__device__ __forceinline__ v2f pk_fma(v2f a, v2f b, v2f c) {   // a*b+c
  v2f d;
  asm("v_pk_fma_f32 %0, %1, %2, %3" : "=v"(d) : "v"(a), "v"(b), "v"(c));
  return d;
}
__device__ __forceinline__ v2f pk_fma_n(v2f a, v2f b, v2f c) { // -a*b+c
  v2f d;
  asm("v_pk_fma_f32 %0, %1, %2, %3 neg_lo:[1,0,0] neg_hi:[1,0,0]"
      : "=v"(d) : "v"(a), "v"(b), "v"(c));
  return d;
}
__device__ __forceinline__ v2f pk_add(v2f a, v2f b) {          // a+b
  v2f d;
  asm("v_pk_add_f32 %0, %1, %2" : "=v"(d) : "v"(a), "v"(b));
  return d;
}
__device__ __forceinline__ v2f pk_sub(v2f a, v2f b) {          // a-b
  v2f d;
  asm("v_pk_add_f32 %0, %1, %2 neg_lo:[0,1] neg_hi:[0,1]"
      : "=v"(d) : "v"(a), "v"(b));
  return d;
}

// ---- wave64 f16x2 DPP reduce: 2 values per op chain ----
#define DPP_H2(x, ctrl, rm, bm, bc)                                          \
  x = x + __builtin_bit_cast(h2, __builtin_amdgcn_update_dpp(                \
      0, __builtin_bit_cast(int, x), ctrl, rm, bm, bc))

__device__ __forceinline__ h2 h2_wave_sum_to_lane63(h2 x) {
  DPP_H2(x, 0x111, 0xf, 0xf, true);   // row_shr:1
  DPP_H2(x, 0x112, 0xf, 0xf, true);   // row_shr:2
  DPP_H2(x, 0x114, 0xf, 0xe, false);  // row_shr:4
  DPP_H2(x, 0x118, 0xf, 0xc, false);  // row_shr:8
  DPP_H2(x, 0x142, 0xa, 0xf, false);  // row_bcast:15
  DPP_H2(x, 0x143, 0xc, 0xf, false);  // row_bcast:31
  return x;                            // lane 63 = full sum (x2)
}

// ---- rcp8: one v_rcp for 4 t-pairs (8 values); emits packed-f16 w ----
__device__ __forceinline__ void rcp8_cvt(const v2f* t, h2* wp) {
  const float p0 = t[0].x * t[0].y, p1 = t[1].x * t[1].y;
  const float p2 = t[2].x * t[2].y, p3 = t[3].x * t[3].y;
  const float q01 = p0 * p1, q23 = p2 * p3;
  const float r   = __builtin_amdgcn_rcpf(q01 * q23);
  const float r01 = q23 * r, r23 = q01 * r;
  const float i0 = p1 * r01, i1 = p0 * r01;
  const float i2 = p3 * r23, i3 = p2 * r23;
  wp[0] = __builtin_amdgcn_cvt_pkrtz(t[0].y * i0, t[0].x * i0);
  wp[1] = __builtin_amdgcn_cvt_pkrtz(t[1].y * i1, t[1].x * i1);
  wp[2] = __builtin_amdgcn_cvt_pkrtz(t[2].y * i2, t[2].x * i2);
  wp[3] = __builtin_amdgcn_cvt_pkrtz(t[3].y * i3, t[3].x * i3);
}
__device__ __forceinline__ void rcp4_cvt(const v2f* t, h2* wp) {
  const float p0 = t[0].x * t[0].y, p1 = t[1].x * t[1].y;
  const float r  = __builtin_amdgcn_rcpf(p0 * p1);
  const float i0 = p1 * r, i1 = p0 * r;
  wp[0] = __builtin_amdgcn_cvt_pkrtz(t[0].y * i0, t[0].x * i0);
  wp[1] = __builtin_amdgcn_cvt_pkrtz(t[1].y * i1, t[1].x * i1);
}

template <int HALF>
__device__ void run_main(const float* __restrict__ soa, int lane,
                         v2f cxp, v2f cyp, v2f czp, float* acc) {
  constexpr int NP = HALF ? 12 : 14;
  const v2f kCA = {CA, CA}, kCY = {CY, CY}, kCZ = {CZ, CZ};
  const v2f k6 = {6.f, 6.f}, k19 = {19.f, 19.f};

  for (int it = 0; it < 8; ++it) {    // neighbors (2i, 2i+1) per lane-step
    const int nb = it * 128 + 2 * lane;
    const v2f pxp = *reinterpret_cast<const v2f*>(&soa[0 * NPTS + nb]);
    const v2f pyp = *reinterpret_cast<const v2f*>(&soa[1 * NPTS + nb]);
    const v2f pzp = *reinterpret_cast<const v2f*>(&soa[2 * NPTS + nb]);
    const v2f f0v = *reinterpret_cast<const v2f*>(&soa[3 * NPTS + nb]);
    const v2f f1v = *reinterpret_cast<const v2f*>(&soa[4 * NPTS + nb]);
    const v2f f2v = *reinterpret_cast<const v2f*>(&soa[5 * NPTS + nb]);

    const v2f dx = pk_sub(pxp, cxp);
    const v2f dy = pk_sub(pyp, cyp);
    const v2f dz = pk_sub(pzp, czp);
    v2f base = pk_fma(dz, dz, k19);
    base = pk_fma(dy, dy, base);
    base = pk_fma(dx, dx, base);

    v2f t[NP];
    if constexpr (HALF == 0) {
      const v2f rx = pk_fma(kCA, dx, base);     // ring x=-2.1213
      const v2f sA = pk_fma  (kCZ, dz, rx);
      const v2f sB = pk_fma_n(kCZ, dz, rx);
      const v2f sC = pk_fma_n(kCY, dz, rx);
      const v2f sD = pk_fma  (kCY, dz, rx);
      t[0]  = pk_fma_n(kCY, dy, sA);  t[1]  = pk_fma(kCY, dy, sA);  // p0,p5
      t[2]  = pk_fma_n(kCY, dy, sB);  t[3]  = pk_fma(kCY, dy, sB);  // p1,p4
      t[4]  = pk_fma_n(kCZ, dy, sC);  t[5]  = pk_fma(kCZ, dy, sC);  // p2,p3
      t[6]  = pk_fma_n(kCZ, dy, sD);  t[7]  = pk_fma(kCZ, dy, sD);  // p7,p6
      t[8]  = pk_fma_n(k6, dy, base); t[9]  = pk_fma(k6, dy, base); // p8,p12
      t[10] = pk_fma_n(k6, dz, base); t[11] = pk_fma(k6, dz, base); // p10,p14
      t[12] = pk_fma  (k6, dx, base); t[13] = pk_fma_n(k6, dx, base);// p24,p25
    } else {
      const v2f rx = pk_fma_n(kCA, dx, base);   // ring x=+2.1213
      const v2f sA = pk_fma_n(kCZ, dz, rx);
      const v2f sB = pk_fma_n(kCY, dz, rx);
      const v2f sC = pk_fma  (kCZ, dz, rx);
      const v2f sD = pk_fma  (kCY, dz, rx);
      const v2f u = pk_add(dy, dz), v = pk_sub(dy, dz);
      t[0]  = pk_fma_n(kCY, dy, sA);  t[1]  = pk_fma(kCY, dy, sA);  // p16,p19
      t[2]  = pk_fma_n(kCZ, dy, sB);  t[3]  = pk_fma(kCZ, dy, sB);  // p17,p18
      t[4]  = pk_fma  (kCY, dy, sC);  t[5]  = pk_fma_n(kCY, dy, sC);// p20,p23
      t[6]  = pk_fma  (kCZ, dy, sD);  t[7]  = pk_fma_n(kCZ, dy, sD);// p21,p22
      t[8]  = pk_fma_n(kCA, u, base); t[9]  = pk_fma(kCA, u, base); // p9,p13
      t[10] = pk_fma  (kCA, v, base); t[11] = pk_fma_n(kCA, v, base);// p11,p15
    }

    h2 wp[NP];
    rcp8_cvt(t + 0, wp + 0);
    rcp8_cvt(t + 4, wp + 4);
    rcp8_cvt(t + 8, wp + 8);
    if constexpr (NP == 14) rcp4_cvt(t + 12, wp + 12);

    const h2 f0p = __builtin_amdgcn_cvt_pkrtz(f0v.x, f0v.y);
    const h2 f1p = __builtin_amdgcn_cvt_pkrtz(f1v.x, f1v.y);
    const h2 f2p = __builtin_amdgcn_cvt_pkrtz(f2v.x, f2v.y);

    #pragma unroll
    for (int j = 0; j < NP; ++j) {
      acc[j * 3 + 0] = __builtin_amdgcn_fdot2(wp[j], f0p, acc[j * 3 + 0], false);
      acc[j * 3 + 1] = __builtin_amdgcn_fdot2(wp[j], f1p, acc[j * 3 + 1], false);
      acc[j * 3 + 2] = __builtin_amdgcn_fdot2(wp[j], f2p, acc[j * 3 + 2], false);
    }
  }
}

// packed f16x2 reduce of NP*3 accs; lane 63 unpacks into f32 sx slot
template <int HALF>
__device__ __forceinline__ void reduce_store(float* acc, int lane, float* sx) {
  constexpr int NP = HALF ? 12 : 14;
  constexpr int NH = NP * 3 / 2;            // 21 or 18 h2 regs
  h2 red[NH];
  #pragma unroll
  for (int p = 0; p < NH; ++p)
    red[p] = __builtin_amdgcn_cvt_pkrtz(acc[2 * p], acc[2 * p + 1]);
  #pragma unroll
  for (int p = 0; p < NH; ++p)
    red[p] = h2_wave_sum_to_lane63(red[p]);
  if (lane == 63) {
    #pragma unroll
    for (int p = 0; p < NH; ++p) {
      const int a0 = 2 * p, a1 = 2 * p + 1;
      const int m0 = (HALF ? M1[a0 / 3] : M0[a0 / 3]);
      const int m1 = (HALF ? M1[a1 / 3] : M0[a1 / 3]);
      sx[m0 * 3 + a0 % 3] = (float)red[p].x;
      sx[m1 * 3 + a1 % 3] = (float)red[p].y;
    }
  }
}

__global__ __launch_bounds__(256, 4) void crossconv_kernel(
    const float* __restrict__ points,  // (2,1024,6)
    const float* __restrict__ W,       // (5,78,6)
    const float* __restrict__ bias,    // (5,6) flat 30
    float* __restrict__ out)           // (2,1024,33)
{
    __shared__ __align__(16) float soa[6 * NPTS];   // 24 KB SoA transpose
    __shared__ __align__(16) float sx[2][80];

    const int tid    = threadIdx.x;
    const int lane   = tid & 63;
    const int w      = tid >> 6;          // wave in block: 0..3
    const int cLocal = w >> 1;            // center within block: 0,1
    const int half   = w & 1;             // probe half: 0,1
    const int G      = blockIdx.x * 2 + cLocal;   // global center 0..2047

    const float* batch = points + (G >> 10) * (NPTS * 6);

    // ---- one-time SoA transpose: thread t handles rows 4t..4t+3 ----
    {
      const float4* src4 = reinterpret_cast<const float4*>(batch) + 6 * tid;
      const float4 q0 = src4[0], q1 = src4[1], q2 = src4[2];
      const float4 q3 = src4[3], q4 = src4[4], q5 = src4[5];
      const int r = 4 * tid;
      // row r+0: q0.x q0.y q0.z q0.w q1.x q1.y
      soa[0*NPTS + r+0] = q0.x; soa[1*NPTS + r+0] = q0.y; soa[2*NPTS + r+0] = q0.z;
      soa[3*NPTS + r+0] = q0.w; soa[4*NPTS + r+0] = q1.x; soa[5*NPTS + r+0] = q1.y;
      // row r+1: q1.z q1.w q2.x q2.y q2.z q2.w
      soa[0*NPTS + r+1] = q1.z; soa[1*NPTS + r+1] = q1.w; soa[2*NPTS + r+1] = q2.x;
      soa[3*NPTS + r+1] = q2.y; soa[4*NPTS + r+1] = q2.z; soa[5*NPTS + r+1] = q2.w;
      // row r+2: q3.x q3.y q3.z q3.w q4.x q4.y
      soa[0*NPTS + r+2] = q3.x; soa[1*NPTS + r+2] = q3.y; soa[2*NPTS + r+2] = q3.z;
      soa[3*NPTS + r+2] = q3.w; soa[4*NPTS + r+2] = q4.x; soa[5*NPTS + r+2] = q4.y;
      // row r+3: q4.z q4.w q5.x q5.y q5.z q5.w
      soa[0*NPTS + r+3] = q4.z; soa[1*NPTS + r+3] = q4.w; soa[2*NPTS + r+3] = q5.x;
      soa[3*NPTS + r+3] = q5.y; soa[4*NPTS + r+3] = q5.z; soa[5*NPTS + r+3] = q5.w;
    }
    __syncthreads();

    const int   ci = ((blockIdx.x & 511) << 1) | cLocal;  // center row in batch
    const float cx = soa[0*NPTS + ci], cy = soa[1*NPTS + ci], cz = soa[2*NPTS + ci];
    const v2f cxp = {cx, cx}, cyp = {cy, cy}, czp = {cz, cz};

    float acc[42];
    #pragma unroll
    for (int j = 0; j < 42; ++j) acc[j] = 0.f;

    if (half == 0) run_main<0>(soa, lane, cxp, cyp, czp, acc);
    else           run_main<1>(soa, lane, cxp, cyp, czp, acc);

    if (half == 0) reduce_store<0>(acc, lane, sx[cLocal]);
    else           reduce_store<1>(acc, lane, sx[cLocal]);
    __syncthreads();

    // tail: waves with half==0 do the 78->30 matmul + coords for their center
    if (half == 0) {
      const float scale = COEFF / (float)NPTS;
      float* orow = out + G * 33;
      if (lane < 30) {
        const int k = lane / 6, o = lane % 6;
        const float* Wk = W + k * (78 * 6) + o;  // W[k, t, o], stride 6 over t
        float h0 = 0.f, h1 = 0.f, h2_ = 0.f, h3 = 0.f;
        const float4* sxv = reinterpret_cast<const float4*>(sx[cLocal]);
        #pragma unroll
        for (int t4 = 0; t4 < 19; ++t4) {
          const float4 v = sxv[t4];
          h0  = fmaf(v.x, Wk[(t4 * 4 + 0) * 6], h0);
          h1  = fmaf(v.y, Wk[(t4 * 4 + 1) * 6], h1);
          h2_ = fmaf(v.z, Wk[(t4 * 4 + 2) * 6], h2_);
          h3  = fmaf(v.w, Wk[(t4 * 4 + 3) * 6], h3);
        }
        const float2 vt = *reinterpret_cast<const float2*>(&sx[cLocal][76]);
        h0 = fmaf(vt.x, Wk[76 * 6], h0);
        h1 = fmaf(vt.y, Wk[77 * 6], h1);
        const float dot = (h0 + h2_) + (h1 + h3);
        float h = fmaf(dot, scale, bias[lane]);
        h = (h > 0.f) ? h : NEG * h;
        orow[3 + lane] = h;
      } else if (lane < 33) {
        orow[lane - 30] = (lane == 30) ? cx : ((lane == 31) ? cy : cz);
      }
    }
}

extern "C" void kernel_launch(void* const* d_in, const int* in_sizes, int n_in,
                              void* d_out, int out_size, void* d_ws, size_t ws_size,
                              hipStream_t stream) {
    const float* points = (const float*)d_in[0];  // 2*1024*6
    const float* W      = (const float*)d_in[1];  // 5*78*6
    const float* bias   = (const float*)d_in[2];  // 30
    float* out          = (float*)d_out;          // 2*1024*33
    // 1024 blocks x 4 waves = 2048 centers x 2 probe-halves
    crossconv_kernel<<<1024, 256, 0, stream>>>(points, W, bias, out);
}

// Round 18
// 21.368 us; speedup vs baseline: 1.1778x; 1.0034x over previous
//
#include <hip/hip_runtime.h>

// CrossConvV2 — R17: R16 (SoA LDS, first win: 23.7->21.4) + latency hiding.
//  1) features pre-converted to f16 at transpose time: inner loop reads h2
//     via ds_read_b32 (3 reads smaller, -3 cvt/iter, LDS 24->18.6KB)
//  2) 2-deep software pipeline: prefetch iter+1's 6 LDS reads into a
//     register double-buffer before computing iter (hides ~120cyc LDS lat)
// All R14/R16 numerics kept: pk-f32 asm, rcp8 batch, fdot2, f16x2 reduce.

#define NPTS   1024
#define COEFF  10.0f
#define NEG    0.3f

typedef float  v2f __attribute__((ext_vector_type(2)));
typedef __fp16 h2  __attribute__((ext_vector_type(2)));

#define CA 4.24264068f   // 2*2.12132034
#define CY 3.91968890f   // 2*1.95984445
#define CZ 1.62358830f   // 2*0.81179415

// slot -> probe index (R9/R12-validated mapping)
constexpr int M0[14] = {0,5, 1,4, 2,3, 7,6, 8,12, 10,14, 24,25};
constexpr int M1[12] = {16,19, 17,18, 20,23, 21,22, 9,13, 11,15};

// ---- VOP3P packed f32 (all operands VGPR pairs; validated R14) ----
__device__ __forceinline__ v2f pk_fma(v2f a, v2f b, v2f c) {   // a*b+c
  v2f d;
  asm("v_pk_fma_f32 %0, %1, %2, %3" : "=v"(d) : "v"(a), "v"(b), "v"(c));
  return d;
}
__device__ __forceinline__ v2f pk_fma_n(v2f a, v2f b, v2f c) { // -a*b+c
  v2f d;
  asm("v_pk_fma_f32 %0, %1, %2, %3 neg_lo:[1,0,0] neg_hi:[1,0,0]"
      : "=v"(d) : "v"(a), "v"(b), "v"(c));
  return d;
}
__device__ __forceinline__ v2f pk_add(v2f a, v2f b) {          // a+b
  v2f d;
  asm("v_pk_add_f32 %0, %1, %2" : "=v"(d) : "v"(a), "v"(b));
  return d;
}
__device__ __forceinline__ v2f pk_sub(v2f a, v2f b) {          // a-b
  v2f d;
  asm("v_pk_add_f32 %0, %1, %2 neg_lo:[0,1] neg_hi:[0,1]"
      : "=v"(d) : "v"(a), "v"(b));
  return d;
}

// ---- wave64 f16x2 DPP reduce: 2 values per op chain ----
#define DPP_H2(x, ctrl, rm, bm, bc)                                          \
  x = x + __builtin_bit_cast(h2, __builtin_amdgcn_update_dpp(                \
      0, __builtin_bit_cast(int, x), ctrl, rm, bm, bc))

__device__ __forceinline__ h2 h2_wave_sum_to_lane63(h2 x) {
  DPP_H2(x, 0x111, 0xf, 0xf, true);   // row_shr:1
  DPP_H2(x, 0x112, 0xf, 0xf, true);   // row_shr:2
  DPP_H2(x, 0x114, 0xf, 0xe, false);  // row_shr:4
  DPP_H2(x, 0x118, 0xf, 0xc, false);  // row_shr:8
  DPP_H2(x, 0x142, 0xa, 0xf, false);  // row_bcast:15
  DPP_H2(x, 0x143, 0xc, 0xf, false);  // row_bcast:31
  return x;                            // lane 63 = full sum (x2)
}

// ---- rcp8: one v_rcp for 4 t-pairs (8 values); emits packed-f16 w ----
__device__ __forceinline__ void rcp8_cvt(const v2f* t, h2* wp) {
  const float p0 = t[0].x * t[0].y, p1 = t[1].x * t[1].y;
  const float p2 = t[2].x * t[2].y, p3 = t[3].x * t[3].y;
  const float q01 = p0 * p1, q23 = p2 * p3;
  const float r   = __builtin_amdgcn_rcpf(q01 * q23);
  const float r01 = q23 * r, r23 = q01 * r;
  const float i0 = p1 * r01, i1 = p0 * r01;
  const float i2 = p3 * r23, i3 = p2 * r23;
  wp[0] = __builtin_amdgcn_cvt_pkrtz(t[0].y * i0, t[0].x * i0);
  wp[1] = __builtin_amdgcn_cvt_pkrtz(t[1].y * i1, t[1].x * i1);
  wp[2] = __builtin_amdgcn_cvt_pkrtz(t[2].y * i2, t[2].x * i2);
  wp[3] = __builtin_amdgcn_cvt_pkrtz(t[3].y * i3, t[3].x * i3);
}
__device__ __forceinline__ void rcp4_cvt(const v2f* t, h2* wp) {
  const float p0 = t[0].x * t[0].y, p1 = t[1].x * t[1].y;
  const float r  = __builtin_amdgcn_rcpf(p0 * p1);
  const float i0 = p1 * r, i1 = p0 * r;
  wp[0] = __builtin_amdgcn_cvt_pkrtz(t[0].y * i0, t[0].x * i0);
  wp[1] = __builtin_amdgcn_cvt_pkrtz(t[1].y * i1, t[1].x * i1);
}

template <int HALF>
__device__ void run_main(const float* __restrict__ sxyz,   // 3*NPTS f32
                         const h2* __restrict__ sfeat,     // 3*(NPTS/2) h2
                         int lane, v2f cxp, v2f cyp, v2f czp, float* acc) {
  constexpr int NP = HALF ? 12 : 14;
  const v2f kCA = {CA, CA}, kCY = {CY, CY}, kCZ = {CZ, CZ};
  const v2f k6 = {6.f, 6.f}, k19 = {19.f, 19.f};

  // register double-buffer for the 2-deep pipeline
  v2f px[2], py[2], pz[2];
  h2  f0[2], f1[2], f2[2];

#define LOADIT(buf, it)                                                       \
  {                                                                           \
    const int nb = (it) * 128 + 2 * lane;                                     \
    const int nh = (it) * 64 + lane;                                          \
    px[buf] = *reinterpret_cast<const v2f*>(&sxyz[0 * NPTS + nb]);            \
    py[buf] = *reinterpret_cast<const v2f*>(&sxyz[1 * NPTS + nb]);            \
    pz[buf] = *reinterpret_cast<const v2f*>(&sxyz[2 * NPTS + nb]);            \
    f0[buf] = sfeat[0 * (NPTS / 2) + nh];                                     \
    f1[buf] = sfeat[1 * (NPTS / 2) + nh];                                     \
    f2[buf] = sfeat[2 * (NPTS / 2) + nh];                                     \
  }

  LOADIT(0, 0);
  #pragma unroll
  for (int it = 0; it < 8; ++it) {
    const int cur = it & 1, nxt = cur ^ 1;
    if (it < 7) LOADIT(nxt, it + 1);      // prefetch overlaps compute below

    const v2f dx = pk_sub(px[cur], cxp);
    const v2f dy = pk_sub(py[cur], cyp);
    const v2f dz = pk_sub(pz[cur], czp);
    v2f base = pk_fma(dz, dz, k19);
    base = pk_fma(dy, dy, base);
    base = pk_fma(dx, dx, base);

    v2f t[NP];
    if constexpr (HALF == 0) {
      const v2f rx = pk_fma(kCA, dx, base);     // ring x=-2.1213
      const v2f sA = pk_fma  (kCZ, dz, rx);
      const v2f sB = pk_fma_n(kCZ, dz, rx);
      const v2f sC = pk_fma_n(kCY, dz, rx);
      const v2f sD = pk_fma  (kCY, dz, rx);
      t[0]  = pk_fma_n(kCY, dy, sA);  t[1]  = pk_fma(kCY, dy, sA);  // p0,p5
      t[2]  = pk_fma_n(kCY, dy, sB);  t[3]  = pk_fma(kCY, dy, sB);  // p1,p4
      t[4]  = pk_fma_n(kCZ, dy, sC);  t[5]  = pk_fma(kCZ, dy, sC);  // p2,p3
      t[6]  = pk_fma_n(kCZ, dy, sD);  t[7]  = pk_fma(kCZ, dy, sD);  // p7,p6
      t[8]  = pk_fma_n(k6, dy, base); t[9]  = pk_fma(k6, dy, base); // p8,p12
      t[10] = pk_fma_n(k6, dz, base); t[11] = pk_fma(k6, dz, base); // p10,p14
      t[12] = pk_fma  (k6, dx, base); t[13] = pk_fma_n(k6, dx, base);// p24,p25
    } else {
      const v2f rx = pk_fma_n(kCA, dx, base);   // ring x=+2.1213
      const v2f sA = pk_fma_n(kCZ, dz, rx);
      const v2f sB = pk_fma_n(kCY, dz, rx);
      const v2f sC = pk_fma  (kCZ, dz, rx);
      const v2f sD = pk_fma  (kCY, dz, rx);
      const v2f u = pk_add(dy, dz), v = pk_sub(dy, dz);
      t[0]  = pk_fma_n(kCY, dy, sA);  t[1]  = pk_fma(kCY, dy, sA);  // p16,p19
      t[2]  = pk_fma_n(kCZ, dy, sB);  t[3]  = pk_fma(kCZ, dy, sB);  // p17,p18
      t[4]  = pk_fma  (kCY, dy, sC);  t[5]  = pk_fma_n(kCY, dy, sC);// p20,p23
      t[6]  = pk_fma  (kCZ, dy, sD);  t[7]  = pk_fma_n(kCZ, dy, sD);// p21,p22
      t[8]  = pk_fma_n(kCA, u, base); t[9]  = pk_fma(kCA, u, base); // p9,p13
      t[10] = pk_fma  (kCA, v, base); t[11] = pk_fma_n(kCA, v, base);// p11,p15
    }

    h2 wp[NP];
    rcp8_cvt(t + 0, wp + 0);
    rcp8_cvt(t + 4, wp + 4);
    rcp8_cvt(t + 8, wp + 8);
    if constexpr (NP == 14) rcp4_cvt(t + 12, wp + 12);

    #pragma unroll
    for (int j = 0; j < NP; ++j) {
      acc[j * 3 + 0] = __builtin_amdgcn_fdot2(wp[j], f0[cur], acc[j * 3 + 0], false);
      acc[j * 3 + 1] = __builtin_amdgcn_fdot2(wp[j], f1[cur], acc[j * 3 + 1], false);
      acc[j * 3 + 2] = __builtin_amdgcn_fdot2(wp[j], f2[cur], acc[j * 3 + 2], false);
    }
  }
#undef LOADIT
}

// packed f16x2 reduce of NP*3 accs; lane 63 unpacks into f32 sx slot
template <int HALF>
__device__ __forceinline__ void reduce_store(float* acc, int lane, float* sx) {
  constexpr int NP = HALF ? 12 : 14;
  constexpr int NH = NP * 3 / 2;            // 21 or 18 h2 regs
  h2 red[NH];
  #pragma unroll
  for (int p = 0; p < NH; ++p)
    red[p] = __builtin_amdgcn_cvt_pkrtz(acc[2 * p], acc[2 * p + 1]);
  #pragma unroll
  for (int p = 0; p < NH; ++p)
    red[p] = h2_wave_sum_to_lane63(red[p]);
  if (lane == 63) {
    #pragma unroll
    for (int p = 0; p < NH; ++p) {
      const int a0 = 2 * p, a1 = 2 * p + 1;
      const int m0 = (HALF ? M1[a0 / 3] : M0[a0 / 3]);
      const int m1 = (HALF ? M1[a1 / 3] : M0[a1 / 3]);
      sx[m0 * 3 + a0 % 3] = (float)red[p].x;
      sx[m1 * 3 + a1 % 3] = (float)red[p].y;
    }
  }
}

__global__ __launch_bounds__(256, 4) void crossconv_kernel(
    const float* __restrict__ points,  // (2,1024,6)
    const float* __restrict__ W,       // (5,78,6)
    const float* __restrict__ bias,    // (5,6) flat 30
    float* __restrict__ out)           // (2,1024,33)
{
    __shared__ __align__(16) float sxyz[3 * NPTS];       // 12 KB coords f32
    __shared__ __align__(16) h2    sfeat[3 * NPTS / 2];  // 6 KB feats f16
    __shared__ __align__(16) float sx[2][80];

    const int tid    = threadIdx.x;
    const int lane   = tid & 63;
    const int w      = tid >> 6;          // wave in block: 0..3
    const int cLocal = w >> 1;            // center within block: 0,1
    const int half   = w & 1;             // probe half: 0,1
    const int G      = blockIdx.x * 2 + cLocal;   // global center 0..2047

    const float* batch = points + (G >> 10) * (NPTS * 6);

    // ---- one-time SoA transpose: thread t handles rows 4t..4t+3 ----
    {
      const float4* src4 = reinterpret_cast<const float4*>(batch) + 6 * tid;
      const float4 q0 = src4[0], q1 = src4[1], q2 = src4[2];
      const float4 q3 = src4[3], q4 = src4[4], q5 = src4[5];
      const int r = 4 * tid;
      // coords f32
      sxyz[0*NPTS + r+0] = q0.x; sxyz[1*NPTS + r+0] = q0.y; sxyz[2*NPTS + r+0] = q0.z;
      sxyz[0*NPTS + r+1] = q1.z; sxyz[1*NPTS + r+1] = q1.w; sxyz[2*NPTS + r+1] = q2.x;
      sxyz[0*NPTS + r+2] = q3.x; sxyz[1*NPTS + r+2] = q3.y; sxyz[2*NPTS + r+2] = q3.z;
      sxyz[0*NPTS + r+3] = q4.z; sxyz[1*NPTS + r+3] = q4.w; sxyz[2*NPTS + r+3] = q5.x;
      // features f16, packed by row pairs (rows r,r+1) and (r+2,r+3)
      const int h = r >> 1;  // h2 index of row pair
      sfeat[0*(NPTS/2) + h+0] = __builtin_amdgcn_cvt_pkrtz(q0.w, q2.y);  // f0 r,r+1
      sfeat[0*(NPTS/2) + h+1] = __builtin_amdgcn_cvt_pkrtz(q3.w, q5.y);  // f0 r+2,r+3
      sfeat[1*(NPTS/2) + h+0] = __builtin_amdgcn_cvt_pkrtz(q1.x, q2.z);  // f1 r,r+1
      sfeat[1*(NPTS/2) + h+1] = __builtin_amdgcn_cvt_pkrtz(q4.x, q5.z);  // f1 r+2,r+3
      sfeat[2*(NPTS/2) + h+0] = __builtin_amdgcn_cvt_pkrtz(q1.y, q2.w);  // f2 r,r+1
      sfeat[2*(NPTS/2) + h+1] = __builtin_amdgcn_cvt_pkrtz(q4.y, q5.w);  // f2 r+2,r+3
    }
    __syncthreads();

    const int   ci = ((blockIdx.x & 511) << 1) | cLocal;  // center row in batch
    const float cx = sxyz[0*NPTS + ci], cy = sxyz[1*NPTS + ci], cz = sxyz[2*NPTS + ci];
    const v2f cxp = {cx, cx}, cyp = {cy, cy}, czp = {cz, cz};

    float acc[42];
    #pragma unroll
    for (int j = 0; j < 42; ++j) acc[j] = 0.f;

    if (half == 0) run_main<0>(sxyz, sfeat, lane, cxp, cyp, czp, acc);
    else           run_main<1>(sxyz, sfeat, lane, cxp, cyp, czp, acc);

    if (half == 0) reduce_store<0>(acc, lane, sx[cLocal]);
    else           reduce_store<1>(acc, lane, sx[cLocal]);
    __syncthreads();

    // tail: waves with half==0 do the 78->30 matmul + coords for their center
    if (half == 0) {
      const float scale = COEFF / (float)NPTS;
      float* orow = out + G * 33;
      if (lane < 30) {
        const int k = lane / 6, o = lane % 6;
        const float* Wk = W + k * (78 * 6) + o;  // W[k, t, o], stride 6 over t
        float h0 = 0.f, h1 = 0.f, h2_ = 0.f, h3 = 0.f;
        const float4* sxv = reinterpret_cast<const float4*>(sx[cLocal]);
        #pragma unroll
        for (int t4 = 0; t4 < 19; ++t4) {
          const float4 v = sxv[t4];
          h0  = fmaf(v.x, Wk[(t4 * 4 + 0) * 6], h0);
          h1  = fmaf(v.y, Wk[(t4 * 4 + 1) * 6], h1);
          h2_ = fmaf(v.z, Wk[(t4 * 4 + 2) * 6], h2_);
          h3  = fmaf(v.w, Wk[(t4 * 4 + 3) * 6], h3);
        }
        const float2 vt = *reinterpret_cast<const float2*>(&sx[cLocal][76]);
        h0 = fmaf(vt.x, Wk[76 * 6], h0);
        h1 = fmaf(vt.y, Wk[77 * 6], h1);
        const float dot = (h0 + h2_) + (h1 + h3);
        float h = fmaf(dot, scale, bias[lane]);
        h = (h > 0.f) ? h : NEG * h;
        orow[3 + lane] = h;
      } else if (lane < 33) {
        orow[lane - 30] = (lane == 30) ? cx : ((lane == 31) ? cy : cz);
      }
    }
}

extern "C" void kernel_launch(void* const* d_in, const int* in_sizes, int n_in,
                              void* d_out, int out_size, void* d_ws, size_t ws_size,
                              hipStream_t stream) {
    const float* points = (const float*)d_in[0];  // 2*1024*6
    const float* W      = (const float*)d_in[1];  // 5*78*6
    const float* bias   = (const float*)d_in[2];  // 30
    float* out          = (float*)d_out;          // 2*1024*33
    // 1024 blocks x 4 waves = 2048 centers x 2 probe-halves
    crossconv_kernel<<<1024, 256, 0, stream>>>(points, W, bias, out);
}